// Round 5
// baseline (128.828 us; speedup 1.0000x reference)
//
#include <hip/hip_runtime.h>

#define HW    256
#define HW2   (HW*HW)
#define C     32
#define CPB   8          // channels per block (channel split = 4)

// 2 outputs per thread: wt payload = 50 VGPRs -> high occupancy, deep MLP.
__global__ __launch_bounds__(256, 5) void ddown_kernel(
    const float* __restrict__ x,
    const float* __restrict__ kern,
    float* __restrict__ out)
{
    const int t   = threadIdx.x;
    const int txq = t & 15;          // 16 column-groups of 2 outputs -> 32 cols
    const int ty  = t >> 4;          // 16 rows
    const int w0  = blockIdx.x * 32;
    const int h0  = blockIdx.y * 16;
    const int b   = blockIdx.z >> 2;
    const int c0  = (blockIdx.z & 3) * CPB;

    const int h = h0 + ty;           // output row
    const int c = w0 + txq * 2;      // first output col (even)

    // ---- softmax weights for this thread's 2 pixels (unnormalized; fold 1/S at end) ----
    const float* kb = kern + (size_t)b * 25 * HW2 + h * HW + c;
    float2 wt[25];
    float sx = 0.f, sy = 0.f;
#pragma unroll
    for (int j = 0; j < 25; ++j) {
        float2 v = *(const float2*)(kb + (size_t)j * HW2);
        v.x = __expf(v.x); v.y = __expf(v.y);
        sx += v.x; sy += v.y;
        wt[j] = v;
    }
    const float ix = 1.f / sx, iy = 1.f / sy;

    // ---- clamped dword offsets, constant across the channel loop ----
    int row_off[5];
#pragma unroll
    for (int di = 0; di < 5; ++di) {
        int hr = h - 2 + di;
        hr = min(max(hr, 0), HW - 1);
        row_off[di] = hr * HW;
    }
    // window cols c-2..c+3 as three clamped float2 pairs
    int p0 = (c - 2) / 2; p0 = min(max(p0, 0), HW / 2 - 1);
    int p1 = c / 2;
    int p2 = (c + 2) / 2; p2 = min(max(p2, 0), HW / 2 - 1);
    const int cp0 = p0 * 2, cp1 = p1 * 2, cp2 = p2 * 2;
    const bool lfix = (c == 0);        // window col -1: clamped pair gave x1, need x0
    const bool rfix = (c == HW - 2);   // window col 256: clamped pair gave x254, need x255

    const float* xc = x + (size_t)(b * C + c0) * HW2;
    float*       ob = out + (size_t)(b * C + c0) * HW2 + h * HW + c;

    for (int cc = 0; cc < CPB; ++cc) {
        float a0 = 0.f, a1 = 0.f;
#pragma unroll
        for (int di = 0; di < 5; ++di) {
            const float* r = xc + row_off[di];
            float2 qa = *(const float2*)(r + cp0);
            float2 qb = *(const float2*)(r + cp1);
            float2 qc = *(const float2*)(r + cp2);
            float e0 = qa.x;
            float e1 = lfix ? qa.x : qa.y;
            float e2 = qb.x, e3 = qb.y;
            float e4 = rfix ? qc.y : qc.x;
            float e5 = qc.y;

            float2 t0 = wt[di * 5 + 0];
            float2 t1 = wt[di * 5 + 1];
            float2 t2 = wt[di * 5 + 2];
            float2 t3 = wt[di * 5 + 3];
            float2 t4 = wt[di * 5 + 4];
            a0 += t0.x * e0 + t1.x * e1 + t2.x * e2 + t3.x * e3 + t4.x * e4;
            a1 += t0.y * e1 + t1.y * e2 + t2.y * e3 + t3.y * e4 + t4.y * e5;
        }
        float2 res = { a0 * ix, a1 * iy };
        *(float2*)ob = res;
        xc += HW2;
        ob += HW2;
    }
}

extern "C" void kernel_launch(void* const* d_in, const int* in_sizes, int n_in,
                              void* d_out, int out_size, void* d_ws, size_t ws_size,
                              hipStream_t stream) {
    const float* x    = (const float*)d_in[0];
    const float* kern = (const float*)d_in[1];
    float* out        = (float*)d_out;

    dim3 grid(HW / 32, HW / 16, 4 * 4);   // (8, 16, 16) = 2048 blocks x 256 threads
    ddown_kernel<<<grid, 256, 0, stream>>>(x, kern, out);
}

// Round 6
// 125.215 us; speedup vs baseline: 1.0289x; 1.0289x over previous
//
#include <hip/hip_runtime.h>

#define HW    256
#define HW2   (HW*HW)
#define C     32
#define CPB   8          // channels per block (channel split = 4)

// 2 outputs/thread, x direct from global (no LDS), explicit 2-deep channel
// software pipeline: ~30 loads in flight per wave during every compute phase.
__global__ __launch_bounds__(256, 4) void ddown_kernel(
    const float* __restrict__ x,
    const float* __restrict__ kern,
    float* __restrict__ out)
{
    const int t   = threadIdx.x;
    const int txq = t & 15;          // 16 column-groups of 2 outputs -> 32 cols
    const int ty  = t >> 4;          // 16 rows
    const int w0  = blockIdx.x * 32;
    const int h0  = blockIdx.y * 16;
    const int b   = blockIdx.z >> 2;
    const int c0  = (blockIdx.z & 3) * CPB;

    const int h = h0 + ty;           // output row
    const int c = w0 + txq * 2;      // first output col (even)

    // ---- clamped dword offsets, constant across the channel loop ----
    int row_off[5];
#pragma unroll
    for (int di = 0; di < 5; ++di) {
        int hr = h - 2 + di;
        hr = min(max(hr, 0), HW - 1);
        row_off[di] = hr * HW;
    }
    int p0 = (c - 2) / 2; p0 = min(max(p0, 0), HW / 2 - 1);
    int p2 = (c + 2) / 2; p2 = min(max(p2, 0), HW / 2 - 1);
    const int cp0 = p0 * 2, cp1 = c, cp2 = p2 * 2;
    const bool lfix = (c == 0);        // window col -1: clamped pair gave x1, need x0
    const bool rfix = (c == HW - 2);   // window col 256: clamped pair gave x254, need x255

    const float* xc = x + (size_t)(b * C + c0) * HW2;

    float2 A0[5], B0[5], Q0[5], A1[5], B1[5], Q1[5];

    auto load_tile = [&](float2* A, float2* B, float2* Q, const float* xb) {
#pragma unroll
        for (int di = 0; di < 5; ++di) {
            const float* r = xb + row_off[di];
            A[di] = *(const float2*)(r + cp0);
            B[di] = *(const float2*)(r + cp1);
            Q[di] = *(const float2*)(r + cp2);
        }
    };

    // issue channel-0 x loads first: their latency hides under the softmax
    load_tile(A0, B0, Q0, xc);

    // ---- softmax weights for this thread's 2 pixels (unnormalized; fold 1/S) ----
    const float* kb = kern + (size_t)b * 25 * HW2 + h * HW + c;
    float2 wt[25];
    float sx = 0.f, sy = 0.f;
#pragma unroll
    for (int j = 0; j < 25; ++j) {
        float2 v = *(const float2*)(kb + (size_t)j * HW2);
        v.x = __expf(v.x); v.y = __expf(v.y);
        sx += v.x; sy += v.y;
        wt[j] = v;
    }
    const float ix = 1.f / sx, iy = 1.f / sy;

    float* ob = out + (size_t)(b * C + c0) * HW2 + h * HW + c;

    auto compute_store = [&](const float2* A, const float2* B, const float2* Q,
                             float* o) {
        float a0 = 0.f, a1 = 0.f, d0 = 0.f, d1 = 0.f;   // split chains
#pragma unroll
        for (int di = 0; di < 5; ++di) {
            float e0 = A[di].x;
            float e1 = lfix ? A[di].x : A[di].y;
            float e2 = B[di].x, e3 = B[di].y;
            float e4 = rfix ? Q[di].y : Q[di].x;
            float e5 = Q[di].y;
            float2 t0 = wt[di * 5 + 0];
            float2 t1 = wt[di * 5 + 1];
            float2 t2 = wt[di * 5 + 2];
            float2 t3 = wt[di * 5 + 3];
            float2 t4 = wt[di * 5 + 4];
            a0 += t0.x * e0 + t1.x * e1 + t2.x * e2;
            d0 += t3.x * e3 + t4.x * e4;
            a1 += t0.y * e1 + t1.y * e2 + t2.y * e3;
            d1 += t3.y * e4 + t4.y * e5;
        }
        float2 res = { (a0 + d0) * ix, (a1 + d1) * iy };
        *(float2*)o = res;
    };

    // ---- 2-deep software-pipelined channel loop (CPB even) ----
#pragma unroll
    for (int cc = 0; cc < CPB; cc += 2) {
        load_tile(A1, B1, Q1, xc + HW2);           // prefetch cc+1
        compute_store(A0, B0, Q0, ob);             // compute cc
        if (cc + 2 < CPB)
            load_tile(A0, B0, Q0, xc + 2 * HW2);   // prefetch cc+2
        compute_store(A1, B1, Q1, ob + HW2);       // compute cc+1
        xc += 2 * HW2;
        ob += 2 * HW2;
    }
}

extern "C" void kernel_launch(void* const* d_in, const int* in_sizes, int n_in,
                              void* d_out, int out_size, void* d_ws, size_t ws_size,
                              hipStream_t stream) {
    const float* x    = (const float*)d_in[0];
    const float* kern = (const float*)d_in[1];
    float* out        = (float*)d_out;

    dim3 grid(HW / 32, HW / 16, 4 * 4);   // (8, 16, 16) = 2048 blocks x 256 threads
    ddown_kernel<<<grid, 256, 0, stream>>>(x, kern, out);
}